// Round 3
// baseline (822.373 us; speedup 1.0000x reference)
//
#include <hip/hip_runtime.h>
#include <hip/hip_bf16.h>

// Problem constants (from reference)
#define BATCH 16
#define SEQ_LEN 50
#define N_POINTS 25
#define SDF_H 100
#define SDF_W 100

// Native clang vector type — __builtin_nontemporal_store requires a native
// vector, not HIP's HIP_vector_type<float,4> class.
typedef float vfloat4 __attribute__((ext_vector_type(4)));

// ---------------------------------------------------------------------------
// Zero-fill kernel: grid-stride over 16 B/lane (full 1 KiB line per wave).
// Nontemporal stores: pure streaming write, no L2 pollution. The rocclr
// fillBufferAligned path showed 4x write amplification (WRITE_SIZE 3.2 GB
// for an 800 MB buffer); this writes exactly 800 MB.
// ---------------------------------------------------------------------------
__global__ void zero_fill_kernel(vfloat4* __restrict__ out, size_t n4) {
    const vfloat4 z = {0.f, 0.f, 0.f, 0.f};
    size_t i = (size_t)blockIdx.x * blockDim.x + threadIdx.x;
    const size_t stride = (size_t)gridDim.x * blockDim.x;
    for (; i < n4; i += stride) {
        __builtin_nontemporal_store(z, &out[i]);
    }
}

// ---------------------------------------------------------------------------
// Scatter kernel: one thread per (b, t, p). Total B*T*P = 20000 threads.
// ---------------------------------------------------------------------------
__global__ void raster_scatter_kernel(const float* __restrict__ x,
                                      const float* __restrict__ resolution,
                                      const float* __restrict__ origin,
                                      float* __restrict__ out) {
    int gid = blockIdx.x * blockDim.x + threadIdx.x;
    const int total = BATCH * SEQ_LEN * N_POINTS;
    if (gid >= total) return;

    int p  = gid % N_POINTS;
    int bt = gid / N_POINTS;        // b*SEQ_LEN + t

    const float px = x[bt * (2 * N_POINTS) + 2 * p];
    const float py = x[bt * (2 * N_POINTS) + 2 * p + 1];

    const float r0 = resolution[bt * 2 + 0];
    const float r1 = resolution[bt * 2 + 1];
    const float o0 = origin[bt * 2 + 0];
    const float o1 = origin[bt * 2 + 1];

    // float32 divide + add, truncate toward zero (matches reference cast).
    int col = (int)(px / r0 + o0);
    int row = (int)(py / r1 + o1);

    // Mirror JAX scatter index clamping (defensive; inputs land in [25,75)).
    col = min(max(col, 0), SDF_W - 1);
    row = min(max(row, 0), SDF_H - 1);

    const size_t off =
        ((((size_t)bt * SDF_H + row) * SDF_W + col) * N_POINTS) + p;
    out[off] = 1.0f;
}

extern "C" void kernel_launch(void* const* d_in, const int* in_sizes, int n_in,
                              void* d_out, int out_size, void* d_ws, size_t ws_size,
                              hipStream_t stream) {
    const float* x          = (const float*)d_in[0];
    const float* resolution = (const float*)d_in[1];
    const float* origin     = (const float*)d_in[2];
    float* out = (float*)d_out;

    // 1) Zero the full output with a vectorized streaming fill.
    //    out_size = 2e8 floats = 5e7 vfloat4s (divisible by 4).
    const size_t n4 = (size_t)out_size / 4;
    const int fill_block = 256;
    const int fill_grid = 2048;  // 8 blocks/CU on 256 CUs; grid-stride loop
    zero_fill_kernel<<<fill_grid, fill_block, 0, stream>>>((vfloat4*)out, n4);

    // 2) Scatter the 20000 ones (stream-ordered after the fill).
    const int total = BATCH * SEQ_LEN * N_POINTS;
    const int block = 256;
    const int grid = (total + block - 1) / block;
    raster_scatter_kernel<<<grid, block, 0, stream>>>(x, resolution, origin, out);
}